// Round 1
// baseline (3983.012 us; speedup 1.0000x reference)
//
#include <hip/hip_runtime.h>
#include <hip/hip_bf16.h>
#include <stdint.h>

#define HDIM   4096
#define TOKENS 4096      // 8*512
#define VOCAB  32000
#define NBATCH 8
#define SEQ    512
#define NTILE  250       // vocab tiles of 128 (32000/128)
#define MTILE  32        // token tiles of 128 (4096/128)
#define BETA_F 0.1f

typedef unsigned short ushortT;
typedef float  f32x4 __attribute__((ext_vector_type(4)));
typedef short  s16x8 __attribute__((ext_vector_type(8)));

// ---------- helpers ----------

__device__ __forceinline__ ushortT f2bf(float f) {
    union { float f; unsigned u; } v; v.f = f;
    unsigned r = v.u + 0x7fffu + ((v.u >> 16) & 1u);   // RNE
    return (ushortT)(r >> 16);
}

__device__ __forceinline__ void async16(const void* g, void* l) {
    __builtin_amdgcn_global_load_lds(
        (const __attribute__((address_space(1))) void*)g,
        (__attribute__((address_space(3))) void*)l, 16, 0, 0);
}

// ---------- fp32 -> bf16 convert (memory bound) ----------

__global__ __launch_bounds__(256) void cvt_kernel(const float* __restrict__ in,
                                                  ushortT* __restrict__ out, long n) {
    long i = ((long)blockIdx.x * 256 + threadIdx.x) * 8;
    if (i + 8 <= n) {
        const float4* p = (const float4*)(in + i);
        float4 a = p[0], b = p[1];
        union { ushortT us[8]; uint4 u4; } pk;
        pk.us[0] = f2bf(a.x); pk.us[1] = f2bf(a.y);
        pk.us[2] = f2bf(a.z); pk.us[3] = f2bf(a.w);
        pk.us[4] = f2bf(b.x); pk.us[5] = f2bf(b.y);
        pk.us[6] = f2bf(b.z); pk.us[7] = f2bf(b.w);
        *(uint4*)(out + i) = pk.u4;
    }
}

// ---------- staging into LDS ----------
// LDS tile layout: [128 rows][64 bf16], row stride 64 elems (128 B).

// bf16 source: global_load_lds, 16 B/lane. One instr = 8 rows (8 lanes/row).
__device__ __forceinline__ void stage_bf16(const ushortT* __restrict__ src, int rbase, int k0,
                                           ushortT* lds, int wid, int lane) {
    const int r8  = lane >> 3;          // row within 8-row group
    const int seg = lane & 7;           // 8-elem (16 B) segment within row
#pragma unroll
    for (int i = 0; i < 4; i++) {
        int rloc = wid * 32 + i * 8;    // wave-uniform
        const ushortT* g = src + (long)(rbase + rloc + r8) * HDIM + k0 + seg * 8;
        async16((const void*)g, (void*)(lds + rloc * 64));
    }
}

// fp32 source: load fp32 -> cvt -> ds_write. 4 threads/row, 16 floats each.
__device__ __forceinline__ void stage_f32(const float* __restrict__ src, int rbase, int k0,
                                          ushortT* lds, int tid) {
    const int seg = tid & 3;            // 16-float segment
    const int r0  = tid >> 2;           // 0..63
#pragma unroll
    for (int s = 0; s < 2; s++) {
        int row = r0 + s * 64;
        const float4* g = (const float4*)(src + (long)(rbase + row) * HDIM + k0 + seg * 16);
        float4 v0 = g[0], v1 = g[1], v2 = g[2], v3 = g[3];
        union { ushortT us[16]; uint4 u4[2]; } pk;
        pk.us[0]  = f2bf(v0.x); pk.us[1]  = f2bf(v0.y); pk.us[2]  = f2bf(v0.z); pk.us[3]  = f2bf(v0.w);
        pk.us[4]  = f2bf(v1.x); pk.us[5]  = f2bf(v1.y); pk.us[6]  = f2bf(v1.z); pk.us[7]  = f2bf(v1.w);
        pk.us[8]  = f2bf(v2.x); pk.us[9]  = f2bf(v2.y); pk.us[10] = f2bf(v2.z); pk.us[11] = f2bf(v2.w);
        pk.us[12] = f2bf(v3.x); pk.us[13] = f2bf(v3.y); pk.us[14] = f2bf(v3.z); pk.us[15] = f2bf(v3.w);
        uint4* d = (uint4*)&lds[row * 64 + seg * 16];
        d[0] = pk.u4[0]; d[1] = pk.u4[1];
    }
}

// ---------- fused GEMM + per-token partial logsumexp stats ----------
// grid: (MTILE, NTILE, 2)  block: 256. Tile 128x128, BK=64, 16x16x32 bf16 MFMA.
// Outputs per z: p_max/p_sum [NTILE][TOKENS], tok [TOKENS] (target logit).

template <bool A_BF16, bool B_BF16>
__global__ __launch_bounds__(256, 2)
void gemm_stats(const void* __restrict__ Ap,
                const void* __restrict__ B0, const void* __restrict__ B1,
                const int* __restrict__ y,
                float* __restrict__ p_max_g, float* __restrict__ p_sum_g,
                float* __restrict__ tok_g) {
    __shared__ ushortT As[128 * 64];
    __shared__ ushortT Bs[128 * 64];
    __shared__ float red_max[2][128];
    __shared__ float red_sum[2][128];

    const int tid  = threadIdx.x;
    const int wid  = tid >> 6;
    const int lane = tid & 63;
    const int quad = lane >> 4;
    const int l15  = lane & 15;

    const int z       = blockIdx.z;
    const int rowbase = blockIdx.x * 128;   // token base
    const int colbase = blockIdx.y * 128;   // vocab base
    const int waveM   = (wid >> 1) * 64;
    const int waveN   = (wid & 1) * 64;

    const void* Bp = (z == 0) ? B0 : B1;
    float* p_max = p_max_g + (long)z * NTILE * TOKENS;
    float* p_sum = p_sum_g + (long)z * NTILE * TOKENS;
    float* tok   = tok_g   + (long)z * TOKENS;

    f32x4 acc[4][4];
#pragma unroll
    for (int i = 0; i < 4; i++)
#pragma unroll
        for (int j = 0; j < 4; j++) acc[i][j] = f32x4{0.f, 0.f, 0.f, 0.f};

    for (int k0 = 0; k0 < HDIM; k0 += 64) {
        if (A_BF16) stage_bf16((const ushortT*)Ap, rowbase, k0, As, wid, lane);
        else        stage_f32((const float*)Ap, rowbase, k0, As, tid);
        if (B_BF16) stage_bf16((const ushortT*)Bp, colbase, k0, Bs, wid, lane);
        else        stage_f32((const float*)Bp, colbase, k0, Bs, tid);
        __syncthreads();
#pragma unroll
        for (int kk = 0; kk < 64; kk += 32) {
            s16x8 af[4], bfr[4];
#pragma unroll
            for (int i = 0; i < 4; i++)
                af[i] = *(const s16x8*)&As[(waveM + i * 16 + l15) * 64 + kk + quad * 8];
#pragma unroll
            for (int j = 0; j < 4; j++)
                bfr[j] = *(const s16x8*)&Bs[(waveN + j * 16 + l15) * 64 + kk + quad * 8];
#pragma unroll
            for (int i = 0; i < 4; i++)
#pragma unroll
                for (int j = 0; j < 4; j++)
                    acc[i][j] = __builtin_amdgcn_mfma_f32_16x16x32_bf16(af[i], bfr[j], acc[i][j], 0, 0, 0);
        }
        __syncthreads();
    }

    // ---- epilogue: per-row (token) max and sum-exp over this block's 128 cols ----
    // C/D layout: row_local = quad*4 + r, col_local = l15.

    // pass 1: wave row-max
#pragma unroll
    for (int i = 0; i < 4; i++) {
#pragma unroll
        for (int r = 0; r < 4; r++) {
            float m = fmaxf(fmaxf(acc[i][0][r], acc[i][1][r]), fmaxf(acc[i][2][r], acc[i][3][r]));
#pragma unroll
            for (int d = 1; d < 16; d <<= 1) m = fmaxf(m, __shfl_xor(m, d, 64));
            if (l15 == 0) red_max[wid & 1][waveM + i * 16 + quad * 4 + r] = m;
        }
    }
    __syncthreads();

    // pass 2: sum-exp with block row-max; capture target logit
#pragma unroll
    for (int i = 0; i < 4; i++) {
#pragma unroll
        for (int r = 0; r < 4; r++) {
            int row = waveM + i * 16 + quad * 4 + r;
            float m = fmaxf(red_max[0][row], red_max[1][row]);
            int label = y[rowbase + row];
            float s = 0.f;
#pragma unroll
            for (int j = 0; j < 4; j++) {
                float v = acc[i][j][r];
                s += __expf(v - m);
                int col = colbase + waveN + j * 16 + l15;
                if (col == label) tok[rowbase + row] = v;
            }
#pragma unroll
            for (int d = 1; d < 16; d <<= 1) s += __shfl_xor(s, d, 64);
            if (l15 == 0) red_sum[wid & 1][row] = s;
        }
    }
    __syncthreads();

    if (tid < 128) {
        float m = fmaxf(red_max[0][tid], red_max[1][tid]);
        float s = red_sum[0][tid] + red_sum[1][tid];
        p_max[(long)blockIdx.y * TOKENS + rowbase + tid] = m;
        p_sum[(long)blockIdx.y * TOKENS + rowbase + tid] = s;
    }
}

// ---------- combine partials -> per-batch avg logp ----------
// grid: 16 blocks = (mat 2) x (batch 8); block 256.

__global__ __launch_bounds__(256) void reduce_logp(const float* __restrict__ p_max,
                                                   const float* __restrict__ p_sum,
                                                   const float* __restrict__ tok,
                                                   const int* __restrict__ y,
                                                   float* __restrict__ pol) {
    const int mat = blockIdx.x >> 3, b = blockIdx.x & 7;
    const float* pm = p_max + (long)mat * NTILE * TOKENS;
    const float* ps = p_sum + (long)mat * NTILE * TOKENS;
    float lsum = 0.f; int lcnt = 0;
    for (int t = threadIdx.x; t < SEQ; t += 256) {
        int token = b * SEQ + t;
        int label = y[token];
        if (label == -100) continue;
        float m = -3.4e38f;
        for (int nt = 0; nt < NTILE; nt++) m = fmaxf(m, pm[(long)nt * TOKENS + token]);
        float s = 0.f;
        for (int nt = 0; nt < NTILE; nt++)
            s += ps[(long)nt * TOKENS + token] * __expf(pm[(long)nt * TOKENS + token] - m);
        float logZ = m + __logf(s);
        lsum += tok[mat * TOKENS + token] - logZ;
        lcnt++;
    }
#pragma unroll
    for (int d = 1; d < 64; d <<= 1) {
        lsum += __shfl_xor(lsum, d, 64);
        lcnt += __shfl_xor(lcnt, d, 64);
    }
    __shared__ float ssum[4]; __shared__ int scnt[4];
    int wid = threadIdx.x >> 6, lane = threadIdx.x & 63;
    if (lane == 0) { ssum[wid] = lsum; scnt[wid] = lcnt; }
    __syncthreads();
    if (threadIdx.x == 0) {
        float S = ssum[0] + ssum[1] + ssum[2] + ssum[3];
        int   C = scnt[0] + scnt[1] + scnt[2] + scnt[3];
        pol[mat * NBATCH + b] = S / (float)(C > 0 ? C : 1);
    }
}

// ---------- final DPO loss ----------

__global__ void dpo_final(const float* __restrict__ pol, float* __restrict__ out) {
    if (threadIdx.x == 0 && blockIdx.x == 0) {
        float accv = 0.f;
        for (int i = 0; i < 4; i++) {
            float pc = pol[i], pr = pol[4 + i];
            float rc = pol[8 + i], rr = pol[12 + i];
            float zz = BETA_F * ((pc - rc) - (pr - rr));
            float l  = (zz > 0.f) ? log1pf(expf(-zz)) : (-zz + log1pf(expf(zz)));
            accv += l;
        }
        out[0] = accv * 0.25f;
    }
}

// ---------- launch ----------

extern "C" void kernel_launch(void* const* d_in, const int* in_sizes, int n_in,
                              void* d_out, int out_size, void* d_ws, size_t ws_size,
                              hipStream_t stream) {
    const float* x  = (const float*)d_in[0];
    const int*   y  = (const int*)d_in[1];
    const float* W  = (const float*)d_in[2];
    const float* rW = (const float*)d_in[3];
    float* out = (float*)d_out;

    char* ws = (char*)d_ws;
    size_t off = 0;
    float* p_max = (float*)(ws + off); off += (size_t)2 * NTILE * TOKENS * 4;  // 8.19 MB
    float* p_sum = (float*)(ws + off); off += (size_t)2 * NTILE * TOKENS * 4;  // 8.19 MB
    float* tok   = (float*)(ws + off); off += (size_t)2 * TOKENS * 4;          // 32 KB
    float* pol   = (float*)(ws + off); off += 256;
    ushortT* xb  = (ushortT*)(ws + off); off += (size_t)TOKENS * HDIM * 2;     // 32 MB
    size_t base_need = off;
    ushortT* Wb  = (ushortT*)(ws + off); off += (size_t)VOCAB * HDIM * 2;      // 256 MB
    ushortT* Rb  = (ushortT*)(ws + off); off += (size_t)VOCAB * HDIM * 2;      // 256 MB
    size_t full_need = off;

    const bool haveX = ws_size >= base_need;
    const bool haveW = ws_size >= full_need;

    dim3 grid(MTILE, NTILE, 2), blk(256, 1, 1);
    if (haveX) {
        cvt_kernel<<<(int)((long)TOKENS * HDIM / 2048), 256, 0, stream>>>(x, xb, (long)TOKENS * HDIM);
        if (haveW) {
            cvt_kernel<<<(int)((long)VOCAB * HDIM / 2048), 256, 0, stream>>>(W, Wb, (long)VOCAB * HDIM);
            cvt_kernel<<<(int)((long)VOCAB * HDIM / 2048), 256, 0, stream>>>(rW, Rb, (long)VOCAB * HDIM);
            gemm_stats<true, true><<<grid, blk, 0, stream>>>(xb, Wb, Rb, y, p_max, p_sum, tok);
        } else {
            gemm_stats<true, false><<<grid, blk, 0, stream>>>(xb, W, rW, y, p_max, p_sum, tok);
        }
    } else {
        gemm_stats<false, false><<<grid, blk, 0, stream>>>(x, W, rW, y, p_max, p_sum, tok);
    }
    reduce_logp<<<16, 256, 0, stream>>>(p_max, p_sum, tok, y, pol);
    dpo_final<<<1, 64, 0, stream>>>(pol, out);
}